// Round 5
// baseline (59.687 us; speedup 1.0000x reference)
//
#include <hip/hip_runtime.h>
#include <math.h>

#define N_NODES 100000
#define N_EDGES 1600000
#define N_UNARY 16

// ---- bin/accumulate geometry -------------------------------------------------
#define NCHUNK 8          // node chunks
#define CH 12500          // nodes per chunk (8*12500 == 100000 exactly)
#define NWG_E 6250        // edge WGs (6250*256 == 1600000 exactly)
#define CAP 128           // record capacity per (edge-WG, chunk); mean 64
#define CAP_SHIFT 7
#define NSLICE 32         // accumulation slices per chunk (grid = 8*32 = 256)
#define PER_SLICE 196     // edge-WGs per slice (196*32 = 6272 >= 6250)

// Fixed-point: per-edge delta in [-0.5,0.5], scale 2^13 -> |q| <= 4096 (14-bit).
// Accumulation packs 3 sums into int64 fields at bits 42/21/0 (21 bits each;
// |sum| <= maxdeg(~70)*4096 = 287k < 2^20, no field overflow).
#define FPSCALE 8192.0f
#define INV_FPSCALE (1.0f / 8192.0f)

typedef unsigned long long u64;

__device__ inline long long pack3(float a, float b, float c) {
    long long qa = (long long)__float2int_rn(a * FPSCALE);
    long long qb = (long long)__float2int_rn(b * FPSCALE);
    long long qc = (long long)__float2int_rn(c * FPSCALE);
    return (qa << 42) + (qb << 21) + qc;
}

// record: local(14) | q0(14) | q1(14) | q2(14)
__device__ inline u64 enc_rec(int local, float a, float b, float c) {
    int qa = __float2int_rn(a * FPSCALE);
    int qb = __float2int_rn(b * FPSCALE);
    int qc = __float2int_rn(c * FPSCALE);
    return ((u64)local << 42) |
           ((u64)((unsigned)qa & 0x3FFFu) << 28) |
           ((u64)((unsigned)qb & 0x3FFFu) << 14) |
           ((u64)((unsigned)qc & 0x3FFFu));
}

// Wave-aggregated staging: for each chunk k, one leader lane bumps cnt[k] by
// the member count; members derive slots from the ballot mask. Cuts LDS
// same-address atomics from 64/wave to <=8/wave (distinct addresses).
__device__ inline void stage_rec(int c, u64 r,
                                 unsigned int* __restrict__ cnt,
                                 u64* __restrict__ stg)
{
    const int lane = threadIdx.x & 63;
    const u64 ltmask = ((u64)1 << lane) - 1;
#pragma unroll
    for (int k = 0; k < NCHUNK; ++k) {
        u64 m = __ballot(c == k);
        if (c == k) {
            int leader = __ffsll((long long)m) - 1;
            unsigned base = 0;
            if (lane == leader)
                base = atomicAdd(&cnt[k], (unsigned)__popcll(m));
            base = (unsigned)__shfl((int)base, leader);
            unsigned slot = base + (unsigned)__popcll(m & ltmask);
            if (slot < CAP) stg[(k << CAP_SHIFT) + slot] = r;
        }
    }
}

// ---------------------------------------------------------------------------
// Kernel A: per-node unary knowledge enhancer (unchanged math).
// ncopies>0: also zeroes the fallback atomic accumulator.
// ---------------------------------------------------------------------------
__global__ __launch_bounds__(256) void kenn_node_kernel(
    const float* __restrict__ unary,
    const float* __restrict__ ucw,
    float* __restrict__ out_nodes,
    float4* __restrict__ u3tab,
    u64* __restrict__ acc,
    int ncopies)
{
    int n = blockIdx.x * blockDim.x + threadIdx.x;
    if (n >= N_NODES) return;

    for (int x = 0; x < ncopies; ++x)
        acc[(size_t)x * N_NODES + n] = 0ull;

    const float w0 = ucw[0], w1 = ucw[1], w2 = ucw[2], w3 = ucw[3];

    const float4* row = reinterpret_cast<const float4*>(unary + (size_t)n * N_UNARY);
    float4 r0 = row[0], r1 = row[1], r2 = row[2], r3 = row[3];

    float x0 = r0.x, x1 = r0.y, x2 = r0.z, x3 = r0.w;
    float x4 = r1.x, x5 = r1.y, x6 = r1.z, x7 = r1.w;
    float x8 = r2.x;

    { // clause 0: idx [0,1], signs [-1,1]
        float t = __expf(-x0 - x1);
        float p1 = 1.0f / (1.0f + t);
        float p0 = 1.0f - p1;
        x0 = r0.x - w0 * p0;
        x1 = r0.y + w0 * p1;
    }
    { // clause 1: idx [2,3], signs [-1,1]
        float t = __expf(-x2 - x3);
        float p1 = 1.0f / (1.0f + t);
        float p0 = 1.0f - p1;
        x2 = r0.z - w1 * p0;
        x3 = r0.w + w1 * p1;
    }
    { // clause 2: idx [4,5,6], signs [-1,1,1]
        float s0 = -x4, s1 = x5, s2 = x6;
        float m = fmaxf(fmaxf(s0, s1), s2);
        float e0 = __expf(s0 - m), e1 = __expf(s1 - m), e2 = __expf(s2 - m);
        float inv = 1.0f / (e0 + e1 + e2);
        x4 = r1.x - w2 * e0 * inv;
        x5 = r1.y + w2 * e1 * inv;
        x6 = r1.z + w2 * e2 * inv;
    }
    { // clause 3: idx [7,8], signs [1,-1]
        float t = __expf(-x8 - x7);
        float p0 = 1.0f / (1.0f + t);
        float p1 = 1.0f - p0;
        x7 = r1.w + w3 * p0;
        x8 = r2.x - w3 * p1;
    }

    float4* orow = reinterpret_cast<float4*>(out_nodes + (size_t)n * N_UNARY);
    orow[0] = make_float4(x0, x1, x2, x3);
    orow[1] = make_float4(x4, x5, x6, x7);
    orow[2] = make_float4(x8, r2.y, r2.z, r2.w);
    orow[3] = r3;

    u3tab[n] = make_float4(x0, x1, x2, x3);
}

// ---------------------------------------------------------------------------
// Device helper: the per-edge binary-clause math.
// ---------------------------------------------------------------------------
__device__ inline void edge_math(float4 a, float4 b, float4 bin,
                                 float w0, float w1, float w2, float w3,
                                 float4& bout,
                                 float& d1c0, float& d1c1, float& d1c2,
                                 float& d2c0, float& d2c1, float& d2c2)
{
    float dbin0, dbin1, dbin2, dbin3;
    { // clause 0: sel=[-a.x,-bin.x,b.x] signs[-1,-1,1] w0
        float s0 = -a.x, s1 = -bin.x, s2 = b.x;
        float m = fmaxf(fmaxf(s0, s1), s2);
        float e0 = __expf(s0 - m), e1 = __expf(s1 - m), e2 = __expf(s2 - m);
        float inv = 1.0f / (e0 + e1 + e2);
        d1c0  = -w0 * e0 * inv;
        dbin0 = -w0 * e1 * inv;
        d2c0  =  w0 * e2 * inv;
    }
    { // clause 1
        float s0 = -a.y, s1 = -bin.y, s2 = b.y;
        float m = fmaxf(fmaxf(s0, s1), s2);
        float e0 = __expf(s0 - m), e1 = __expf(s1 - m), e2 = __expf(s2 - m);
        float inv = 1.0f / (e0 + e1 + e2);
        d1c1  = -w1 * e0 * inv;
        dbin1 = -w1 * e1 * inv;
        d2c1  =  w1 * e2 * inv;
    }
    { // clause 2: sel=[-bin.z,bin.w] signs[-1,1] w2
        float t = __expf(-bin.z - bin.w);
        float p1 = 1.0f / (1.0f + t);
        float p0 = 1.0f - p1;
        dbin2 = -w2 * p0;
        dbin3 =  w2 * p1;
    }
    { // clause 3: sel=[-a.z,b.z] signs[-1,1] w3
        float t = __expf(-a.z - b.z);
        float p1 = 1.0f / (1.0f + t);
        float p0 = 1.0f - p1;
        d1c2 = -w3 * p0;
        d2c2 =  w3 * p1;
    }
    bout = make_float4(bin.x + dbin0, bin.y + dbin1, bin.z + dbin2, bin.w + dbin3);
}

// ---------------------------------------------------------------------------
// Kernel B (main path): per-edge compute + chunk-binned record emission.
// No global atomics; wave-aggregated LDS counters; wave-parallel dump.
// ---------------------------------------------------------------------------
__global__ __launch_bounds__(256) void kenn_edge_bin_kernel(
    const float* __restrict__ binary,
    const int* __restrict__ idx1,
    const int* __restrict__ idx2,
    const float* __restrict__ bcw,
    const float4* __restrict__ u3tab,
    u64* __restrict__ rec,
    unsigned int* __restrict__ counts,
    float* __restrict__ out_binary)
{
    __shared__ unsigned int cnt[NCHUNK];
    __shared__ u64 stg[NCHUNK * CAP];

    if (threadIdx.x < NCHUNK) cnt[threadIdx.x] = 0;
    __syncthreads();

    const int e = blockIdx.x * 256 + threadIdx.x;
    const float w0 = bcw[0], w1 = bcw[1], w2 = bcw[2], w3 = bcw[3];

    int i1 = idx1[e];
    int i2 = idx2[e];
    float4 bin = reinterpret_cast<const float4*>(binary)[e];
    float4 a = u3tab[i1];
    float4 b = u3tab[i2];

    float4 bout;
    float d1c0, d1c1, d1c2, d2c0, d2c1, d2c2;
    edge_math(a, b, bin, w0, w1, w2, w3, bout, d1c0, d1c1, d1c2, d2c0, d2c1, d2c2);

    reinterpret_cast<float4*>(out_binary)[e] = bout;

    { // endpoint 1
        int c1 = i1 / CH;
        stage_rec(c1, enc_rec(i1 - c1 * CH, d1c0, d1c1, d1c2), cnt, stg);
    }
    { // endpoint 2
        int c2 = i2 / CH;
        stage_rec(c2, enc_rec(i2 - c2 * CH, d2c0, d2c1, d2c2), cnt, stg);
    }
    __syncthreads();

    // wave-parallel coalesced dump: wave w handles chunks 2w, 2w+1
    const size_t wg = blockIdx.x;
    const int wv = threadIdx.x >> 6;
    const int ln = threadIdx.x & 63;
#pragma unroll
    for (int j = 0; j < 2; ++j) {
        int c = wv * 2 + j;
        unsigned n = min(cnt[c], (unsigned)CAP);
        for (unsigned i = ln; i < n; i += 64)
            rec[((wg * NCHUNK + c) << CAP_SHIFT) + i] = stg[(c << CAP_SHIFT) + i];
    }
    if (threadIdx.x < NCHUNK)
        counts[wg * NCHUNK + threadIdx.x] = min(cnt[threadIdx.x], (unsigned)CAP);
}

// ---------------------------------------------------------------------------
// Kernel C (main path): per-(chunk,slice) LDS accumulation of records.
// Dynamic LDS: CH * 8 = 100000 bytes of int64 accumulators.
// ---------------------------------------------------------------------------
__global__ __launch_bounds__(1024) void kenn_accum_kernel(
    const u64* __restrict__ rec,
    const unsigned int* __restrict__ counts,
    u64* __restrict__ partial)
{
    extern __shared__ u64 accL[];          // CH entries
    __shared__ unsigned int cnts[PER_SLICE];

    const int wg = blockIdx.x;             // 0..NCHUNK*NSLICE-1
    const int c = wg >> 5;                 // / NSLICE
    const int s = wg & (NSLICE - 1);
    const int pbase = s * PER_SLICE;
    const int pend = min(pbase + PER_SLICE, NWG_E);
    const int np = pend - pbase;

    for (int j = threadIdx.x; j < np; j += blockDim.x)
        cnts[j] = counts[(size_t)(pbase + j) * NCHUNK + c];
    for (int i = threadIdx.x; i < CH; i += blockDim.x)
        accL[i] = 0ull;
    __syncthreads();

    const int wave = threadIdx.x >> 6;
    const int lane = threadIdx.x & 63;
    for (int j = wave; j < np; j += 16) {
        const int cnt = (int)cnts[j];
        const u64* rp = rec + (((size_t)(pbase + j) * NCHUNK + c) << CAP_SHIFT);
        for (int i = lane; i < cnt; i += 64) {
            u64 r = rp[i];
            int local = (int)(r >> 42);
            long long q0 = (long long)(((long long)(r << 22)) >> 50);
            long long q1 = (long long)(((long long)(r << 36)) >> 50);
            long long q2 = (long long)(((long long)(r << 50)) >> 50);
            u64 pkt = (u64)((q0 << 42) + (q1 << 21) + q2);
            atomicAdd(&accL[local], pkt);
        }
    }
    __syncthreads();

    u64* pout = partial + (size_t)wg * CH;
    for (int i = threadIdx.x; i < CH; i += blockDim.x)
        pout[i] = accL[i];
}

// ---------------------------------------------------------------------------
// Kernel D (main path): sum NSLICE partials per node, decode, write row 0.
// ---------------------------------------------------------------------------
__global__ __launch_bounds__(256) void kenn_final_kernel(
    const u64* __restrict__ partial,
    const float4* __restrict__ u3tab,
    float* __restrict__ out_nodes)
{
    int n = blockIdx.x * blockDim.x + threadIdx.x;
    if (n >= N_NODES) return;

    int c = n / CH;
    int local = n - c * CH;
    const u64* pp = partial + (size_t)(c * NSLICE) * CH + local;

    long long t = 0;
#pragma unroll
    for (int s = 0; s < NSLICE; ++s)
        t += (long long)pp[(size_t)s * CH];

    long long qc = (t << 43) >> 43;        // sign-extend low 21 bits
    t = (t - qc) >> 21;
    long long qb = (t << 43) >> 43;
    long long qa = (t - qb) >> 21;

    float4 u = u3tab[n];
    reinterpret_cast<float4*>(out_nodes + (size_t)n * N_UNARY)[0] =
        make_float4(u.x + (float)qa * INV_FPSCALE,
                    u.y + (float)qb * INV_FPSCALE,
                    u.z + (float)qc * INV_FPSCALE,
                    u.w);
}

// ---------------------------------------------------------------------------
// Fallback path (ws too small): single-copy packed global atomics.
// ---------------------------------------------------------------------------
__global__ __launch_bounds__(256) void kenn_edge_atomic_kernel(
    const float* __restrict__ binary,
    const int* __restrict__ idx1,
    const int* __restrict__ idx2,
    const float* __restrict__ bcw,
    const float4* __restrict__ u3tab,
    u64* __restrict__ acc,
    float* __restrict__ out_binary)
{
    int e = blockIdx.x * blockDim.x + threadIdx.x;
    if (e >= N_EDGES) return;

    const float w0 = bcw[0], w1 = bcw[1], w2 = bcw[2], w3 = bcw[3];

    int i1 = idx1[e];
    int i2 = idx2[e];
    float4 bin = reinterpret_cast<const float4*>(binary)[e];
    float4 a = u3tab[i1];
    float4 b = u3tab[i2];

    float4 bout;
    float d1c0, d1c1, d1c2, d2c0, d2c1, d2c2;
    edge_math(a, b, bin, w0, w1, w2, w3, bout, d1c0, d1c1, d1c2, d2c0, d2c1, d2c2);

    reinterpret_cast<float4*>(out_binary)[e] = bout;

    atomicAdd(&acc[i1], (u64)pack3(d1c0, d1c1, d1c2));
    atomicAdd(&acc[i2], (u64)pack3(d2c0, d2c1, d2c2));
}

__global__ __launch_bounds__(256) void kenn_fixup_kernel(
    const u64* __restrict__ acc,
    const float4* __restrict__ u3tab,
    float* __restrict__ out_nodes)
{
    int n = blockIdx.x * blockDim.x + threadIdx.x;
    if (n >= N_NODES) return;

    long long t = (long long)acc[n];
    long long qc = (t << 43) >> 43;
    t = (t - qc) >> 21;
    long long qb = (t << 43) >> 43;
    long long qa = (t - qb) >> 21;

    float4 u = u3tab[n];
    reinterpret_cast<float4*>(out_nodes + (size_t)n * N_UNARY)[0] =
        make_float4(u.x + (float)qa * INV_FPSCALE,
                    u.y + (float)qb * INV_FPSCALE,
                    u.z + (float)qc * INV_FPSCALE,
                    u.w);
}

extern "C" void kernel_launch(void* const* d_in, const int* in_sizes, int n_in,
                              void* d_out, int out_size, void* d_ws, size_t ws_size,
                              hipStream_t stream) {
    const float* unary    = (const float*)d_in[0];
    const float* binary   = (const float*)d_in[1];
    const int*   index1   = (const int*)d_in[2];
    const int*   index2   = (const int*)d_in[3];
    const float* unary_cw = (const float*)d_in[4];
    const float* bin_cw   = (const float*)d_in[5];

    float* out_nodes  = (float*)d_out;
    float* out_binary = (float*)d_out + (size_t)N_NODES * N_UNARY;

    // ws layout (main path):
    //   u3tab    : N_NODES * 16B                       =  1.6 MB
    //   rec      : NWG_E * NCHUNK * CAP * 8B           = 51.2 MB
    //   counts   : NWG_E * NCHUNK * 4B                 =  0.2 MB
    //   partials : (NCHUNK*NSLICE) * CH * 8B           = 25.6 MB
    char* base = (char*)d_ws;
    size_t off_u3   = 0;
    size_t off_rec  = off_u3 + (size_t)N_NODES * 16;
    size_t off_cnt  = off_rec + (size_t)NWG_E * NCHUNK * CAP * 8;
    size_t off_par  = (off_cnt + (size_t)NWG_E * NCHUNK * 4 + 255) & ~(size_t)255;
    size_t need     = off_par + (size_t)NCHUNK * NSLICE * CH * 8;

    float4* u3tab = (float4*)(base + off_u3);

    dim3 blockN(256), gridN((N_NODES + 255) / 256);
    dim3 blockE(256), gridE(NWG_E);

    if (ws_size >= need) {
        u64* rec = (u64*)(base + off_rec);
        unsigned int* counts = (unsigned int*)(base + off_cnt);
        u64* partials = (u64*)(base + off_par);

        kenn_node_kernel<<<gridN, blockN, 0, stream>>>(
            unary, unary_cw, out_nodes, u3tab, (u64*)nullptr, 0);

        kenn_edge_bin_kernel<<<gridE, blockE, 0, stream>>>(
            binary, index1, index2, bin_cw, u3tab, rec, counts, out_binary);

        kenn_accum_kernel<<<dim3(NCHUNK * NSLICE), dim3(1024), CH * 8, stream>>>(
            rec, counts, partials);

        kenn_final_kernel<<<gridN, blockN, 0, stream>>>(partials, u3tab, out_nodes);
    } else {
        u64* acc = (u64*)(base + (size_t)N_NODES * 16);
        kenn_node_kernel<<<gridN, blockN, 0, stream>>>(
            unary, unary_cw, out_nodes, u3tab, acc, 1);
        kenn_edge_atomic_kernel<<<gridE, blockE, 0, stream>>>(
            binary, index1, index2, bin_cw, u3tab, acc, out_binary);
        kenn_fixup_kernel<<<gridN, blockN, 0, stream>>>(acc, u3tab, out_nodes);
    }
}

// Round 6
// 52.745 us; speedup vs baseline: 1.1316x; 1.1316x over previous
//
#include <hip/hip_runtime.h>
#include <math.h>

#define N_NODES 100000
#define N_EDGES 1600000
#define N_UNARY 16

// ---- bin/accumulate geometry ----------------------------------------------
#define NCHUNK 16         // node chunks
#define CH 6250           // nodes per chunk (16*6250 == 100000 exactly)
#define EPW 512           // edges per workgroup (2 per thread)
#define NWG_E 3125        // edge WGs (3125*512 == 1600000 exactly)
#define CAP 112           // record capacity per (edge-WG, chunk); mean 64, ~6.2 sigma
#define NSLICE 16         // accumulation slices per chunk (grid = 16*16 = 256)
#define PER_SLICE 196     // edge-WGs per slice (196*16 = 3136 >= 3125)

// Fixed-point: per-edge delta in [-0.5,0.5], scale 2^13 -> |q| <= 4096 (14-bit).
// Accumulation packs 3 sums into int64 fields at bits 42/21/0 (21 bits each;
// |sum| <= maxdeg(~70)*4096 = 287k < 2^20, no field overflow).
#define FPSCALE 8192.0f
#define INV_FPSCALE (1.0f / 8192.0f)

typedef unsigned long long u64;

__device__ inline long long pack3(float a, float b, float c) {
    long long qa = (long long)__float2int_rn(a * FPSCALE);
    long long qb = (long long)__float2int_rn(b * FPSCALE);
    long long qc = (long long)__float2int_rn(c * FPSCALE);
    return (qa << 42) + (qb << 21) + qc;
}

// record: local(14) | q0(14) | q1(14) | q2(14)
__device__ inline u64 enc_rec(int local, float a, float b, float c) {
    int qa = __float2int_rn(a * FPSCALE);
    int qb = __float2int_rn(b * FPSCALE);
    int qc = __float2int_rn(c * FPSCALE);
    return ((u64)local << 42) |
           ((u64)((unsigned)qa & 0x3FFFu) << 28) |
           ((u64)((unsigned)qb & 0x3FFFu) << 14) |
           ((u64)((unsigned)qc & 0x3FFFu));
}

// Simple per-thread staging (round-4 winner). Overflow (beyond CAP) spills to
// a rare device-scope packed atomic -> exact for any index distribution.
__device__ inline void stage_rec(int node, float d0, float d1, float d2,
                                 unsigned int* __restrict__ cnt,
                                 u64* __restrict__ stg,
                                 u64* __restrict__ spill)
{
    int c = node / CH;
    int local = node - c * CH;
    unsigned slot = atomicAdd(&cnt[c], 1u);
    if (slot < CAP)
        stg[c * CAP + slot] = enc_rec(local, d0, d1, d2);
    else
        atomicAdd(&spill[node], (u64)pack3(d0, d1, d2));
}

// ---------------------------------------------------------------------------
// Kernel A: per-node unary knowledge enhancer. Also zeroes the spill acc.
// ---------------------------------------------------------------------------
__global__ __launch_bounds__(256) void kenn_node_kernel(
    const float* __restrict__ unary,
    const float* __restrict__ ucw,
    float* __restrict__ out_nodes,
    float4* __restrict__ u3tab,
    u64* __restrict__ acc)
{
    int n = blockIdx.x * blockDim.x + threadIdx.x;
    if (n >= N_NODES) return;

    acc[n] = 0ull;

    const float w0 = ucw[0], w1 = ucw[1], w2 = ucw[2], w3 = ucw[3];

    const float4* row = reinterpret_cast<const float4*>(unary + (size_t)n * N_UNARY);
    float4 r0 = row[0], r1 = row[1], r2 = row[2], r3 = row[3];

    float x0 = r0.x, x1 = r0.y, x2 = r0.z, x3 = r0.w;
    float x4 = r1.x, x5 = r1.y, x6 = r1.z, x7 = r1.w;
    float x8 = r2.x;

    { // clause 0: idx [0,1], signs [-1,1]
        float t = __expf(-x0 - x1);
        float p1 = 1.0f / (1.0f + t);
        float p0 = 1.0f - p1;
        x0 = r0.x - w0 * p0;
        x1 = r0.y + w0 * p1;
    }
    { // clause 1: idx [2,3], signs [-1,1]
        float t = __expf(-x2 - x3);
        float p1 = 1.0f / (1.0f + t);
        float p0 = 1.0f - p1;
        x2 = r0.z - w1 * p0;
        x3 = r0.w + w1 * p1;
    }
    { // clause 2: idx [4,5,6], signs [-1,1,1]
        float s0 = -x4, s1 = x5, s2 = x6;
        float m = fmaxf(fmaxf(s0, s1), s2);
        float e0 = __expf(s0 - m), e1 = __expf(s1 - m), e2 = __expf(s2 - m);
        float inv = 1.0f / (e0 + e1 + e2);
        x4 = r1.x - w2 * e0 * inv;
        x5 = r1.y + w2 * e1 * inv;
        x6 = r1.z + w2 * e2 * inv;
    }
    { // clause 3: idx [7,8], signs [1,-1]
        float t = __expf(-x8 - x7);
        float p0 = 1.0f / (1.0f + t);
        float p1 = 1.0f - p0;
        x7 = r1.w + w3 * p0;
        x8 = r2.x - w3 * p1;
    }

    float4* orow = reinterpret_cast<float4*>(out_nodes + (size_t)n * N_UNARY);
    orow[0] = make_float4(x0, x1, x2, x3);
    orow[1] = make_float4(x4, x5, x6, x7);
    orow[2] = make_float4(x8, r2.y, r2.z, r2.w);
    orow[3] = r3;

    u3tab[n] = make_float4(x0, x1, x2, x3);
}

// ---------------------------------------------------------------------------
// Device helper: the per-edge binary-clause math.
// ---------------------------------------------------------------------------
__device__ inline void edge_math(float4 a, float4 b, float4 bin,
                                 float w0, float w1, float w2, float w3,
                                 float4& bout,
                                 float& d1c0, float& d1c1, float& d1c2,
                                 float& d2c0, float& d2c1, float& d2c2)
{
    float dbin0, dbin1, dbin2, dbin3;
    { // clause 0: sel=[-a.x,-bin.x,b.x] signs[-1,-1,1] w0
        float s0 = -a.x, s1 = -bin.x, s2 = b.x;
        float m = fmaxf(fmaxf(s0, s1), s2);
        float e0 = __expf(s0 - m), e1 = __expf(s1 - m), e2 = __expf(s2 - m);
        float inv = 1.0f / (e0 + e1 + e2);
        d1c0  = -w0 * e0 * inv;
        dbin0 = -w0 * e1 * inv;
        d2c0  =  w0 * e2 * inv;
    }
    { // clause 1
        float s0 = -a.y, s1 = -bin.y, s2 = b.y;
        float m = fmaxf(fmaxf(s0, s1), s2);
        float e0 = __expf(s0 - m), e1 = __expf(s1 - m), e2 = __expf(s2 - m);
        float inv = 1.0f / (e0 + e1 + e2);
        d1c1  = -w1 * e0 * inv;
        dbin1 = -w1 * e1 * inv;
        d2c1  =  w1 * e2 * inv;
    }
    { // clause 2: sel=[-bin.z,bin.w] signs[-1,1] w2
        float t = __expf(-bin.z - bin.w);
        float p1 = 1.0f / (1.0f + t);
        float p0 = 1.0f - p1;
        dbin2 = -w2 * p0;
        dbin3 =  w2 * p1;
    }
    { // clause 3: sel=[-a.z,b.z] signs[-1,1] w3
        float t = __expf(-a.z - b.z);
        float p1 = 1.0f / (1.0f + t);
        float p0 = 1.0f - p1;
        d1c2 = -w3 * p0;
        d2c2 =  w3 * p1;
    }
    bout = make_float4(bin.x + dbin0, bin.y + dbin1, bin.z + dbin2, bin.w + dbin3);
}

// ---------------------------------------------------------------------------
// Kernel B: per-edge compute + chunk-binned record emission.
// 2 edges/thread for MLP: both gather chains issue before either is consumed.
// ---------------------------------------------------------------------------
__global__ __launch_bounds__(256) void kenn_edge_bin_kernel(
    const float* __restrict__ binary,
    const int* __restrict__ idx1,
    const int* __restrict__ idx2,
    const float* __restrict__ bcw,
    const float4* __restrict__ u3tab,
    u64* __restrict__ rec,
    unsigned int* __restrict__ counts,
    u64* __restrict__ spill,
    float* __restrict__ out_binary)
{
    __shared__ unsigned int cnt[NCHUNK];
    __shared__ u64 stg[NCHUNK * CAP];

    if (threadIdx.x < NCHUNK) cnt[threadIdx.x] = 0;
    __syncthreads();

    const float w0 = bcw[0], w1 = bcw[1], w2 = bcw[2], w3 = bcw[3];

    const int e0 = blockIdx.x * EPW + threadIdx.x;
    const int e1 = e0 + 256;

    // issue all independent loads up front (2 idx pairs, 2 binaries, 4 gathers)
    int i1a = idx1[e0], i2a = idx2[e0];
    int i1b = idx1[e1], i2b = idx2[e1];
    float4 bina = reinterpret_cast<const float4*>(binary)[e0];
    float4 binb = reinterpret_cast<const float4*>(binary)[e1];
    float4 aa = u3tab[i1a];
    float4 ba = u3tab[i2a];
    float4 ab = u3tab[i1b];
    float4 bb = u3tab[i2b];

    float4 bouta, boutb;
    float a1c0, a1c1, a1c2, a2c0, a2c1, a2c2;
    float b1c0, b1c1, b1c2, b2c0, b2c1, b2c2;
    edge_math(aa, ba, bina, w0, w1, w2, w3, bouta, a1c0, a1c1, a1c2, a2c0, a2c1, a2c2);
    edge_math(ab, bb, binb, w0, w1, w2, w3, boutb, b1c0, b1c1, b1c2, b2c0, b2c1, b2c2);

    reinterpret_cast<float4*>(out_binary)[e0] = bouta;
    reinterpret_cast<float4*>(out_binary)[e1] = boutb;

    stage_rec(i1a, a1c0, a1c1, a1c2, cnt, stg, spill);
    stage_rec(i2a, a2c0, a2c1, a2c2, cnt, stg, spill);
    stage_rec(i1b, b1c0, b1c1, b1c2, cnt, stg, spill);
    stage_rec(i2b, b2c0, b2c1, b2c2, cnt, stg, spill);
    __syncthreads();

    // wave-parallel coalesced dump: wave w handles chunks 4w..4w+3
    const size_t wg = blockIdx.x;
    const int wv = threadIdx.x >> 6;
    const int ln = threadIdx.x & 63;
#pragma unroll
    for (int j = 0; j < 4; ++j) {
        int c = wv * 4 + j;
        unsigned n = min(cnt[c], (unsigned)CAP);
        for (unsigned i = ln; i < n; i += 64)
            rec[((wg * NCHUNK + c) * CAP) + i] = stg[c * CAP + i];
    }
    if (threadIdx.x < NCHUNK)
        counts[wg * NCHUNK + threadIdx.x] = min(cnt[threadIdx.x], (unsigned)CAP);
}

// ---------------------------------------------------------------------------
// Kernel C: per-(chunk,slice) LDS accumulation of records.
// Dynamic LDS: CH * 8 = 50000 bytes of int64 accumulators.
// ---------------------------------------------------------------------------
__global__ __launch_bounds__(1024) void kenn_accum_kernel(
    const u64* __restrict__ rec,
    const unsigned int* __restrict__ counts,
    u64* __restrict__ partial)
{
    extern __shared__ u64 accL[];          // CH entries
    __shared__ unsigned int cnts[PER_SLICE];

    const int wg = blockIdx.x;             // 0..NCHUNK*NSLICE-1
    const int c = wg >> 4;                 // / NSLICE
    const int s = wg & (NSLICE - 1);
    const int pbase = s * PER_SLICE;
    const int pend = min(pbase + PER_SLICE, NWG_E);
    const int np = pend - pbase;

    for (int j = threadIdx.x; j < np; j += blockDim.x)
        cnts[j] = counts[(size_t)(pbase + j) * NCHUNK + c];
    for (int i = threadIdx.x; i < CH; i += blockDim.x)
        accL[i] = 0ull;
    __syncthreads();

    const int wave = threadIdx.x >> 6;
    const int lane = threadIdx.x & 63;
    for (int j = wave; j < np; j += 16) {
        const int cnt = (int)cnts[j];
        const u64* rp = rec + ((size_t)(pbase + j) * NCHUNK + c) * CAP;
        for (int i = lane; i < cnt; i += 64) {
            u64 r = rp[i];
            int local = (int)(r >> 42);
            long long q0 = ((long long)(r << 22)) >> 50;
            long long q1 = ((long long)(r << 36)) >> 50;
            long long q2 = ((long long)(r << 50)) >> 50;
            u64 pkt = (u64)((q0 << 42) + (q1 << 21) + q2);
            atomicAdd(&accL[local], pkt);
        }
    }
    __syncthreads();

    u64* pout = partial + (size_t)wg * CH;
    for (int i = threadIdx.x; i < CH; i += blockDim.x)
        pout[i] = accL[i];
}

// ---------------------------------------------------------------------------
// Kernel D: sum NSLICE partials + spill per node, decode, write row 0.
// ---------------------------------------------------------------------------
__global__ __launch_bounds__(256) void kenn_final_kernel(
    const u64* __restrict__ partial,
    const u64* __restrict__ spill,
    const float4* __restrict__ u3tab,
    float* __restrict__ out_nodes)
{
    int n = blockIdx.x * blockDim.x + threadIdx.x;
    if (n >= N_NODES) return;

    int c = n / CH;
    int local = n - c * CH;
    const u64* pp = partial + (size_t)(c * NSLICE) * CH + local;

    long long t = (long long)spill[n];
#pragma unroll
    for (int s = 0; s < NSLICE; ++s)
        t += (long long)pp[(size_t)s * CH];

    long long qc = (t << 43) >> 43;        // sign-extend low 21 bits
    t = (t - qc) >> 21;
    long long qb = (t << 43) >> 43;
    long long qa = (t - qb) >> 21;

    float4 u = u3tab[n];
    reinterpret_cast<float4*>(out_nodes + (size_t)n * N_UNARY)[0] =
        make_float4(u.x + (float)qa * INV_FPSCALE,
                    u.y + (float)qb * INV_FPSCALE,
                    u.z + (float)qc * INV_FPSCALE,
                    u.w);
}

// ---------------------------------------------------------------------------
// Fallback path (ws too small): single-copy packed global atomics.
// ---------------------------------------------------------------------------
__global__ __launch_bounds__(256) void kenn_edge_atomic_kernel(
    const float* __restrict__ binary,
    const int* __restrict__ idx1,
    const int* __restrict__ idx2,
    const float* __restrict__ bcw,
    const float4* __restrict__ u3tab,
    u64* __restrict__ acc,
    float* __restrict__ out_binary)
{
    int e = blockIdx.x * blockDim.x + threadIdx.x;
    if (e >= N_EDGES) return;

    const float w0 = bcw[0], w1 = bcw[1], w2 = bcw[2], w3 = bcw[3];

    int i1 = idx1[e];
    int i2 = idx2[e];
    float4 bin = reinterpret_cast<const float4*>(binary)[e];
    float4 a = u3tab[i1];
    float4 b = u3tab[i2];

    float4 bout;
    float d1c0, d1c1, d1c2, d2c0, d2c1, d2c2;
    edge_math(a, b, bin, w0, w1, w2, w3, bout, d1c0, d1c1, d1c2, d2c0, d2c1, d2c2);

    reinterpret_cast<float4*>(out_binary)[e] = bout;

    atomicAdd(&acc[i1], (u64)pack3(d1c0, d1c1, d1c2));
    atomicAdd(&acc[i2], (u64)pack3(d2c0, d2c1, d2c2));
}

__global__ __launch_bounds__(256) void kenn_fixup_kernel(
    const u64* __restrict__ acc,
    const float4* __restrict__ u3tab,
    float* __restrict__ out_nodes)
{
    int n = blockIdx.x * blockDim.x + threadIdx.x;
    if (n >= N_NODES) return;

    long long t = (long long)acc[n];
    long long qc = (t << 43) >> 43;
    t = (t - qc) >> 21;
    long long qb = (t << 43) >> 43;
    long long qa = (t - qb) >> 21;

    float4 u = u3tab[n];
    reinterpret_cast<float4*>(out_nodes + (size_t)n * N_UNARY)[0] =
        make_float4(u.x + (float)qa * INV_FPSCALE,
                    u.y + (float)qb * INV_FPSCALE,
                    u.z + (float)qc * INV_FPSCALE,
                    u.w);
}

extern "C" void kernel_launch(void* const* d_in, const int* in_sizes, int n_in,
                              void* d_out, int out_size, void* d_ws, size_t ws_size,
                              hipStream_t stream) {
    const float* unary    = (const float*)d_in[0];
    const float* binary   = (const float*)d_in[1];
    const int*   index1   = (const int*)d_in[2];
    const int*   index2   = (const int*)d_in[3];
    const float* unary_cw = (const float*)d_in[4];
    const float* bin_cw   = (const float*)d_in[5];

    float* out_nodes  = (float*)d_out;
    float* out_binary = (float*)d_out + (size_t)N_NODES * N_UNARY;

    // ws layout:
    //   u3tab    : N_NODES * 16B                       =  1.6 MB
    //   acc      : N_NODES * 8B (spill / fallback)     =  0.8 MB
    //   rec      : NWG_E * NCHUNK * CAP * 8B           = 44.8 MB
    //   counts   : NWG_E * NCHUNK * 4B                 =  0.2 MB
    //   partials : (NCHUNK*NSLICE) * CH * 8B           = 12.8 MB
    char* base = (char*)d_ws;
    size_t off_u3   = 0;
    size_t off_acc  = off_u3 + (size_t)N_NODES * 16;
    size_t off_rec  = off_acc + (size_t)N_NODES * 8;
    size_t off_cnt  = off_rec + (size_t)NWG_E * NCHUNK * CAP * 8;
    size_t off_par  = (off_cnt + (size_t)NWG_E * NCHUNK * 4 + 255) & ~(size_t)255;
    size_t need     = off_par + (size_t)NCHUNK * NSLICE * CH * 8;

    float4* u3tab = (float4*)(base + off_u3);
    u64* acc = (u64*)(base + off_acc);

    dim3 blockN(256), gridN((N_NODES + 255) / 256);

    kenn_node_kernel<<<gridN, blockN, 0, stream>>>(unary, unary_cw, out_nodes,
                                                   u3tab, acc);

    if (ws_size >= need) {
        u64* rec = (u64*)(base + off_rec);
        unsigned int* counts = (unsigned int*)(base + off_cnt);
        u64* partials = (u64*)(base + off_par);

        kenn_edge_bin_kernel<<<dim3(NWG_E), dim3(256), 0, stream>>>(
            binary, index1, index2, bin_cw, u3tab, rec, counts, acc, out_binary);

        kenn_accum_kernel<<<dim3(NCHUNK * NSLICE), dim3(1024), CH * 8, stream>>>(
            rec, counts, partials);

        kenn_final_kernel<<<gridN, blockN, 0, stream>>>(partials, acc, u3tab,
                                                        out_nodes);
    } else {
        kenn_edge_atomic_kernel<<<dim3((N_EDGES + 255) / 256), dim3(256), 0, stream>>>(
            binary, index1, index2, bin_cw, u3tab, acc, out_binary);
        kenn_fixup_kernel<<<gridN, blockN, 0, stream>>>(acc, u3tab, out_nodes);
    }
}

// Round 7
// 52.145 us; speedup vs baseline: 1.1446x; 1.0115x over previous
//
#include <hip/hip_runtime.h>
#include <math.h>

#define N_NODES 100000
#define N_EDGES 1600000
#define N_UNARY 16

// ---- bin/accumulate geometry ----------------------------------------------
#define NCHUNK 16         // node chunks
#define CH 6250           // nodes per chunk (16*6250 == 100000 exactly)
#define EPW 512           // edges per workgroup (2 per thread)
#define NWG_E 3125        // edge WGs (3125*512 == 1600000 exactly)
#define CAP 112           // record capacity per (edge-WG, chunk); mean 64, ~6.2 sigma
#define NSLICE 16         // accumulation slices per chunk (grid = 16*16 = 256)
#define PER_SLICE 196     // edge-WGs per slice (196*16 = 3136 >= 3125)

// Fixed-point: per-edge delta in [-0.5,0.5], scale 2^13 -> |q| <= 4096 (14-bit).
// Accumulation packs 3 sums into int64 fields at bits 42/21/0 (21 bits each;
// |sum| <= maxdeg(~70)*4096 = 287k < 2^20, no field overflow).
#define FPSCALE 8192.0f
#define INV_FPSCALE (1.0f / 8192.0f)

typedef unsigned long long u64;

__device__ inline long long pack3(float a, float b, float c) {
    long long qa = (long long)__float2int_rn(a * FPSCALE);
    long long qb = (long long)__float2int_rn(b * FPSCALE);
    long long qc = (long long)__float2int_rn(c * FPSCALE);
    return (qa << 42) + (qb << 21) + qc;
}

// record: local(14) | q0(14) | q1(14) | q2(14)
__device__ inline u64 enc_rec(int local, float a, float b, float c) {
    int qa = __float2int_rn(a * FPSCALE);
    int qb = __float2int_rn(b * FPSCALE);
    int qc = __float2int_rn(c * FPSCALE);
    return ((u64)local << 42) |
           ((u64)((unsigned)qa & 0x3FFFu) << 28) |
           ((u64)((unsigned)qb & 0x3FFFu) << 14) |
           ((u64)((unsigned)qc & 0x3FFFu));
}

// bf16 pack/unpack (RNE). Only the EDGE-GATHERED copies are bf16; the base
// values used to build the output stay fp32.
__device__ inline unsigned f2bf(float f) {
    union { float f; unsigned u; } v; v.f = f;
    return ((v.u + 0x7FFFu + ((v.u >> 16) & 1u)) >> 16) & 0xFFFFu;
}
__device__ inline float bf2f(unsigned h) {
    union { unsigned u; float f; } v; v.u = h << 16; return v.f;
}

// Per-thread staging; overflow beyond CAP spills to a rare device-scope
// packed atomic -> exact for any index distribution.
__device__ inline void stage_rec(int node, float d0, float d1, float d2,
                                 unsigned int* __restrict__ cnt,
                                 u64* __restrict__ stg,
                                 u64* __restrict__ spill)
{
    int c = node / CH;
    int local = node - c * CH;
    unsigned slot = atomicAdd(&cnt[c], 1u);
    if (slot < CAP)
        stg[c * CAP + slot] = enc_rec(local, d0, d1, d2);
    else
        atomicAdd(&spill[node], (u64)pack3(d0, d1, d2));
}

// ---------------------------------------------------------------------------
// Kernel A: per-node unary knowledge enhancer. Writes fp32 u3tab (for the
// final kernel), bf16-packed u3bf (for the edge gather), zeroes spill acc.
// ---------------------------------------------------------------------------
__global__ __launch_bounds__(256) void kenn_node_kernel(
    const float* __restrict__ unary,
    const float* __restrict__ ucw,
    float* __restrict__ out_nodes,
    float4* __restrict__ u3tab,
    u64* __restrict__ u3bf,
    u64* __restrict__ acc)
{
    int n = blockIdx.x * blockDim.x + threadIdx.x;
    if (n >= N_NODES) return;

    acc[n] = 0ull;

    const float w0 = ucw[0], w1 = ucw[1], w2 = ucw[2], w3 = ucw[3];

    const float4* row = reinterpret_cast<const float4*>(unary + (size_t)n * N_UNARY);
    float4 r0 = row[0], r1 = row[1], r2 = row[2], r3 = row[3];

    float x0 = r0.x, x1 = r0.y, x2 = r0.z, x3 = r0.w;
    float x4 = r1.x, x5 = r1.y, x6 = r1.z, x7 = r1.w;
    float x8 = r2.x;

    { // clause 0: idx [0,1], signs [-1,1]
        float t = __expf(-x0 - x1);
        float p1 = 1.0f / (1.0f + t);
        float p0 = 1.0f - p1;
        x0 = r0.x - w0 * p0;
        x1 = r0.y + w0 * p1;
    }
    { // clause 1: idx [2,3], signs [-1,1]
        float t = __expf(-x2 - x3);
        float p1 = 1.0f / (1.0f + t);
        float p0 = 1.0f - p1;
        x2 = r0.z - w1 * p0;
        x3 = r0.w + w1 * p1;
    }
    { // clause 2: idx [4,5,6], signs [-1,1,1]
        float s0 = -x4, s1 = x5, s2 = x6;
        float m = fmaxf(fmaxf(s0, s1), s2);
        float e0 = __expf(s0 - m), e1 = __expf(s1 - m), e2 = __expf(s2 - m);
        float inv = 1.0f / (e0 + e1 + e2);
        x4 = r1.x - w2 * e0 * inv;
        x5 = r1.y + w2 * e1 * inv;
        x6 = r1.z + w2 * e2 * inv;
    }
    { // clause 3: idx [7,8], signs [1,-1]
        float t = __expf(-x8 - x7);
        float p0 = 1.0f / (1.0f + t);
        float p1 = 1.0f - p0;
        x7 = r1.w + w3 * p0;
        x8 = r2.x - w3 * p1;
    }

    float4* orow = reinterpret_cast<float4*>(out_nodes + (size_t)n * N_UNARY);
    orow[0] = make_float4(x0, x1, x2, x3);
    orow[1] = make_float4(x4, x5, x6, x7);
    orow[2] = make_float4(x8, r2.y, r2.z, r2.w);
    orow[3] = r3;

    u3tab[n] = make_float4(x0, x1, x2, x3);
    u3bf[n] = (u64)f2bf(x0) | ((u64)f2bf(x1) << 16)
            | ((u64)f2bf(x2) << 32) | ((u64)f2bf(x3) << 48);
}

// ---------------------------------------------------------------------------
// Device helper: the per-edge binary-clause math.
// ---------------------------------------------------------------------------
__device__ inline void edge_math(float ax, float ay, float az,
                                 float bx, float by, float bz, float4 bin,
                                 float w0, float w1, float w2, float w3,
                                 float4& bout,
                                 float& d1c0, float& d1c1, float& d1c2,
                                 float& d2c0, float& d2c1, float& d2c2)
{
    float dbin0, dbin1, dbin2, dbin3;
    { // clause 0: sel=[-ax,-bin.x,bx] signs[-1,-1,1] w0
        float s0 = -ax, s1 = -bin.x, s2 = bx;
        float m = fmaxf(fmaxf(s0, s1), s2);
        float e0 = __expf(s0 - m), e1 = __expf(s1 - m), e2 = __expf(s2 - m);
        float inv = 1.0f / (e0 + e1 + e2);
        d1c0  = -w0 * e0 * inv;
        dbin0 = -w0 * e1 * inv;
        d2c0  =  w0 * e2 * inv;
    }
    { // clause 1
        float s0 = -ay, s1 = -bin.y, s2 = by;
        float m = fmaxf(fmaxf(s0, s1), s2);
        float e0 = __expf(s0 - m), e1 = __expf(s1 - m), e2 = __expf(s2 - m);
        float inv = 1.0f / (e0 + e1 + e2);
        d1c1  = -w1 * e0 * inv;
        dbin1 = -w1 * e1 * inv;
        d2c1  =  w1 * e2 * inv;
    }
    { // clause 2: sel=[-bin.z,bin.w] signs[-1,1] w2
        float t = __expf(-bin.z - bin.w);
        float p1 = 1.0f / (1.0f + t);
        float p0 = 1.0f - p1;
        dbin2 = -w2 * p0;
        dbin3 =  w2 * p1;
    }
    { // clause 3: sel=[-az,bz] signs[-1,1] w3
        float t = __expf(-az - bz);
        float p1 = 1.0f / (1.0f + t);
        float p0 = 1.0f - p1;
        d1c2 = -w3 * p0;
        d2c2 =  w3 * p1;
    }
    bout = make_float4(bin.x + dbin0, bin.y + dbin1, bin.z + dbin2, bin.w + dbin3);
}

// Agent-scope (L1-bypassing) 8B gather of bf16-packed u values.
__device__ inline void gather_u3(const u64* __restrict__ u3bf, int i,
                                 float& x, float& y, float& z)
{
    u64 g = __hip_atomic_load(&u3bf[i], __ATOMIC_RELAXED, __HIP_MEMORY_SCOPE_AGENT);
    x = bf2f((unsigned)(g & 0xFFFFu));
    y = bf2f((unsigned)((g >> 16) & 0xFFFFu));
    z = bf2f((unsigned)((g >> 32) & 0xFFFFu));
}

// ---------------------------------------------------------------------------
// Kernel B: per-edge compute + chunk-binned record emission. 2 edges/thread.
// ---------------------------------------------------------------------------
__global__ __launch_bounds__(256) void kenn_edge_bin_kernel(
    const float* __restrict__ binary,
    const int* __restrict__ idx1,
    const int* __restrict__ idx2,
    const float* __restrict__ bcw,
    const u64* __restrict__ u3bf,
    u64* __restrict__ rec,
    unsigned int* __restrict__ counts,
    u64* __restrict__ spill,
    float* __restrict__ out_binary)
{
    __shared__ unsigned int cnt[NCHUNK];
    __shared__ u64 stg[NCHUNK * CAP];

    if (threadIdx.x < NCHUNK) cnt[threadIdx.x] = 0;
    __syncthreads();

    const float w0 = bcw[0], w1 = bcw[1], w2 = bcw[2], w3 = bcw[3];

    const int e0 = blockIdx.x * EPW + threadIdx.x;
    const int e1 = e0 + 256;

    // issue all independent loads up front
    int i1a = idx1[e0], i2a = idx2[e0];
    int i1b = idx1[e1], i2b = idx2[e1];
    float4 bina = reinterpret_cast<const float4*>(binary)[e0];
    float4 binb = reinterpret_cast<const float4*>(binary)[e1];

    float aax, aay, aaz, bax, bay, baz;
    float abx, aby, abz, bbx, bby, bbz;
    gather_u3(u3bf, i1a, aax, aay, aaz);
    gather_u3(u3bf, i2a, bax, bay, baz);
    gather_u3(u3bf, i1b, abx, aby, abz);
    gather_u3(u3bf, i2b, bbx, bby, bbz);

    float4 bouta, boutb;
    float a1c0, a1c1, a1c2, a2c0, a2c1, a2c2;
    float b1c0, b1c1, b1c2, b2c0, b2c1, b2c2;
    edge_math(aax, aay, aaz, bax, bay, baz, bina, w0, w1, w2, w3,
              bouta, a1c0, a1c1, a1c2, a2c0, a2c1, a2c2);
    edge_math(abx, aby, abz, bbx, bby, bbz, binb, w0, w1, w2, w3,
              boutb, b1c0, b1c1, b1c2, b2c0, b2c1, b2c2);

    reinterpret_cast<float4*>(out_binary)[e0] = bouta;
    reinterpret_cast<float4*>(out_binary)[e1] = boutb;

    stage_rec(i1a, a1c0, a1c1, a1c2, cnt, stg, spill);
    stage_rec(i2a, a2c0, a2c1, a2c2, cnt, stg, spill);
    stage_rec(i1b, b1c0, b1c1, b1c2, cnt, stg, spill);
    stage_rec(i2b, b2c0, b2c1, b2c2, cnt, stg, spill);
    __syncthreads();

    // wave-parallel coalesced dump: wave w handles chunks 4w..4w+3
    const size_t wg = blockIdx.x;
    const int wv = threadIdx.x >> 6;
    const int ln = threadIdx.x & 63;
#pragma unroll
    for (int j = 0; j < 4; ++j) {
        int c = wv * 4 + j;
        unsigned n = min(cnt[c], (unsigned)CAP);
        for (unsigned i = ln; i < n; i += 64)
            rec[((wg * NCHUNK + c) * CAP) + i] = stg[c * CAP + i];
    }
    if (threadIdx.x < NCHUNK)
        counts[wg * NCHUNK + threadIdx.x] = min(cnt[threadIdx.x], (unsigned)CAP);
}

// ---------------------------------------------------------------------------
// Kernel C: per-(chunk,slice) LDS accumulation of records.
// Dynamic LDS: CH * 8 = 50000 bytes of int64 accumulators.
// ---------------------------------------------------------------------------
__global__ __launch_bounds__(1024) void kenn_accum_kernel(
    const u64* __restrict__ rec,
    const unsigned int* __restrict__ counts,
    u64* __restrict__ partial)
{
    extern __shared__ u64 accL[];          // CH entries
    __shared__ unsigned int cnts[PER_SLICE];

    const int wg = blockIdx.x;             // 0..NCHUNK*NSLICE-1
    const int c = wg >> 4;                 // / NSLICE
    const int s = wg & (NSLICE - 1);
    const int pbase = s * PER_SLICE;
    const int pend = min(pbase + PER_SLICE, NWG_E);
    const int np = pend - pbase;

    for (int j = threadIdx.x; j < np; j += blockDim.x)
        cnts[j] = counts[(size_t)(pbase + j) * NCHUNK + c];
    for (int i = threadIdx.x; i < CH; i += blockDim.x)
        accL[i] = 0ull;
    __syncthreads();

    const int wave = threadIdx.x >> 6;
    const int lane = threadIdx.x & 63;
    for (int j = wave; j < np; j += 16) {
        const int cnt = (int)cnts[j];
        const u64* rp = rec + ((size_t)(pbase + j) * NCHUNK + c) * CAP;
        for (int i = lane; i < cnt; i += 64) {
            u64 r = rp[i];
            int local = (int)(r >> 42);
            long long q0 = ((long long)(r << 22)) >> 50;
            long long q1 = ((long long)(r << 36)) >> 50;
            long long q2 = ((long long)(r << 50)) >> 50;
            u64 pkt = (u64)((q0 << 42) + (q1 << 21) + q2);
            atomicAdd(&accL[local], pkt);
        }
    }
    __syncthreads();

    u64* pout = partial + (size_t)wg * CH;
    for (int i = threadIdx.x; i < CH; i += blockDim.x)
        pout[i] = accL[i];
}

// ---------------------------------------------------------------------------
// Kernel D: sum NSLICE partials + spill per node, decode, write row 0.
// ---------------------------------------------------------------------------
__global__ __launch_bounds__(256) void kenn_final_kernel(
    const u64* __restrict__ partial,
    const u64* __restrict__ spill,
    const float4* __restrict__ u3tab,
    float* __restrict__ out_nodes)
{
    int n = blockIdx.x * blockDim.x + threadIdx.x;
    if (n >= N_NODES) return;

    int c = n / CH;
    int local = n - c * CH;
    const u64* pp = partial + (size_t)(c * NSLICE) * CH + local;

    long long t = (long long)spill[n];
#pragma unroll
    for (int s = 0; s < NSLICE; ++s)
        t += (long long)pp[(size_t)s * CH];

    long long qc = (t << 43) >> 43;        // sign-extend low 21 bits
    t = (t - qc) >> 21;
    long long qb = (t << 43) >> 43;
    long long qa = (t - qb) >> 21;

    float4 u = u3tab[n];
    reinterpret_cast<float4*>(out_nodes + (size_t)n * N_UNARY)[0] =
        make_float4(u.x + (float)qa * INV_FPSCALE,
                    u.y + (float)qb * INV_FPSCALE,
                    u.z + (float)qc * INV_FPSCALE,
                    u.w);
}

// ---------------------------------------------------------------------------
// Fallback path (ws too small): single-copy packed global atomics.
// ---------------------------------------------------------------------------
__global__ __launch_bounds__(256) void kenn_edge_atomic_kernel(
    const float* __restrict__ binary,
    const int* __restrict__ idx1,
    const int* __restrict__ idx2,
    const float* __restrict__ bcw,
    const float4* __restrict__ u3tab,
    u64* __restrict__ acc,
    float* __restrict__ out_binary)
{
    int e = blockIdx.x * blockDim.x + threadIdx.x;
    if (e >= N_EDGES) return;

    const float w0 = bcw[0], w1 = bcw[1], w2 = bcw[2], w3 = bcw[3];

    int i1 = idx1[e];
    int i2 = idx2[e];
    float4 bin = reinterpret_cast<const float4*>(binary)[e];
    float4 a = u3tab[i1];
    float4 b = u3tab[i2];

    float4 bout;
    float d1c0, d1c1, d1c2, d2c0, d2c1, d2c2;
    edge_math(a.x, a.y, a.z, b.x, b.y, b.z, bin, w0, w1, w2, w3,
              bout, d1c0, d1c1, d1c2, d2c0, d2c1, d2c2);

    reinterpret_cast<float4*>(out_binary)[e] = bout;

    atomicAdd(&acc[i1], (u64)pack3(d1c0, d1c1, d1c2));
    atomicAdd(&acc[i2], (u64)pack3(d2c0, d2c1, d2c2));
}

__global__ __launch_bounds__(256) void kenn_fixup_kernel(
    const u64* __restrict__ acc,
    const float4* __restrict__ u3tab,
    float* __restrict__ out_nodes)
{
    int n = blockIdx.x * blockDim.x + threadIdx.x;
    if (n >= N_NODES) return;

    long long t = (long long)acc[n];
    long long qc = (t << 43) >> 43;
    t = (t - qc) >> 21;
    long long qb = (t << 43) >> 43;
    long long qa = (t - qb) >> 21;

    float4 u = u3tab[n];
    reinterpret_cast<float4*>(out_nodes + (size_t)n * N_UNARY)[0] =
        make_float4(u.x + (float)qa * INV_FPSCALE,
                    u.y + (float)qb * INV_FPSCALE,
                    u.z + (float)qc * INV_FPSCALE,
                    u.w);
}

extern "C" void kernel_launch(void* const* d_in, const int* in_sizes, int n_in,
                              void* d_out, int out_size, void* d_ws, size_t ws_size,
                              hipStream_t stream) {
    const float* unary    = (const float*)d_in[0];
    const float* binary   = (const float*)d_in[1];
    const int*   index1   = (const int*)d_in[2];
    const int*   index2   = (const int*)d_in[3];
    const float* unary_cw = (const float*)d_in[4];
    const float* bin_cw   = (const float*)d_in[5];

    float* out_nodes  = (float*)d_out;
    float* out_binary = (float*)d_out + (size_t)N_NODES * N_UNARY;

    // ws layout:
    //   u3tab    : N_NODES * 16B                       =  1.6 MB
    //   u3bf     : N_NODES * 8B  (bf16-packed gather)  =  0.8 MB
    //   acc      : N_NODES * 8B  (spill / fallback)    =  0.8 MB
    //   rec      : NWG_E * NCHUNK * CAP * 8B           = 44.8 MB
    //   counts   : NWG_E * NCHUNK * 4B                 =  0.2 MB
    //   partials : (NCHUNK*NSLICE) * CH * 8B           = 12.8 MB
    char* base = (char*)d_ws;
    size_t off_u3   = 0;
    size_t off_bf   = off_u3 + (size_t)N_NODES * 16;
    size_t off_acc  = off_bf + (size_t)N_NODES * 8;
    size_t off_rec  = off_acc + (size_t)N_NODES * 8;
    size_t off_cnt  = off_rec + (size_t)NWG_E * NCHUNK * CAP * 8;
    size_t off_par  = (off_cnt + (size_t)NWG_E * NCHUNK * 4 + 255) & ~(size_t)255;
    size_t need     = off_par + (size_t)NCHUNK * NSLICE * CH * 8;

    float4* u3tab = (float4*)(base + off_u3);
    u64* u3bf = (u64*)(base + off_bf);
    u64* acc = (u64*)(base + off_acc);

    dim3 blockN(256), gridN((N_NODES + 255) / 256);

    kenn_node_kernel<<<gridN, blockN, 0, stream>>>(unary, unary_cw, out_nodes,
                                                   u3tab, u3bf, acc);

    if (ws_size >= need) {
        u64* rec = (u64*)(base + off_rec);
        unsigned int* counts = (unsigned int*)(base + off_cnt);
        u64* partials = (u64*)(base + off_par);

        kenn_edge_bin_kernel<<<dim3(NWG_E), dim3(256), 0, stream>>>(
            binary, index1, index2, bin_cw, u3bf, rec, counts, acc, out_binary);

        kenn_accum_kernel<<<dim3(NCHUNK * NSLICE), dim3(1024), CH * 8, stream>>>(
            rec, counts, partials);

        kenn_final_kernel<<<gridN, blockN, 0, stream>>>(partials, acc, u3tab,
                                                        out_nodes);
    } else {
        kenn_edge_atomic_kernel<<<dim3((N_EDGES + 255) / 256), dim3(256), 0, stream>>>(
            binary, index1, index2, bin_cw, u3tab, acc, out_binary);
        kenn_fixup_kernel<<<gridN, blockN, 0, stream>>>(acc, u3tab, out_nodes);
    }
}